// Round 1
// baseline (3028.541 us; speedup 1.0000x reference)
//
#include <hip/hip_runtime.h>

#define D 256
#define BM 128
#define BN 128
#define BK 16
#define LDSP 132

// ---------------- CSR build ----------------

__global__ void hist_kernel(const int* __restrict__ dst, int* __restrict__ cnt, int E){
  int e = blockIdx.x * blockDim.x + threadIdx.x;
  if (e < E) atomicAdd(&cnt[dst[e]], 1);
}

__global__ void scan_kernel(const int* __restrict__ cnt, int* __restrict__ rowptr, int n){
  __shared__ int sums[1024];
  int tid = threadIdx.x;
  int chunk = (n + 1023) >> 10;
  int start = tid * chunk;
  int end = start + chunk; if (end > n) end = n;
  int s = 0;
  if (start < n) for (int i = start; i < end; ++i) s += cnt[i];
  sums[tid] = s;
  __syncthreads();
  for (int off = 1; off < 1024; off <<= 1){
    int v = (tid >= off) ? sums[tid - off] : 0;
    __syncthreads();
    sums[tid] += v;
    __syncthreads();
  }
  int run = (tid == 0) ? 0 : sums[tid - 1];
  if (start < n){
    for (int i = start; i < end; ++i){ rowptr[i] = run; run += cnt[i]; }
    if (end == n) rowptr[n] = run;
  }
}

__global__ void copy_kernel(const int* __restrict__ a, int* __restrict__ b, int n){
  int i = blockIdx.x * blockDim.x + threadIdx.x;
  if (i < n) b[i] = a[i];
}

__global__ void scatter_kernel(const int* __restrict__ src, const int* __restrict__ dst,
                               int* __restrict__ cursor, int* __restrict__ col, int E){
  int e = blockIdx.x * blockDim.x + threadIdx.x;
  if (e < E){
    int pos = atomicAdd(&cursor[dst[e]], 1);
    col[pos] = src[e];
  }
}

// ---------------- aggregation: s = x + sum_{src in N(dst)} x[src] ----------------
// one wave (64 lanes) per dst node, float4 per lane (64*16B = 1KB row)

__global__ void agg_kernel(const float4* __restrict__ X, const int* __restrict__ rowptr,
                           const int* __restrict__ col, float4* __restrict__ S, int M){
  int gid = blockIdx.x * blockDim.x + threadIdx.x;
  int node = gid >> 6;
  int lane = gid & 63;
  if (node >= M) return;
  float4 acc = X[(size_t)node * 64 + lane];
  int p = rowptr[node], p1 = rowptr[node + 1];
  for (; p + 2 <= p1; p += 2){
    int s0 = col[p], s1 = col[p + 1];
    float4 v0 = X[(size_t)s0 * 64 + lane];
    float4 v1 = X[(size_t)s1 * 64 + lane];
    acc.x += v0.x; acc.y += v0.y; acc.z += v0.z; acc.w += v0.w;
    acc.x += v1.x; acc.y += v1.y; acc.z += v1.z; acc.w += v1.w;
  }
  if (p < p1){
    int s0 = col[p];
    float4 v0 = X[(size_t)s0 * 64 + lane];
    acc.x += v0.x; acc.y += v0.y; acc.z += v0.z; acc.w += v0.w;
  }
  S[(size_t)node * 64 + lane] = acc;
}

// ---------------- f32 GEMM: C = relu(A @ W + bias) [+ R]; optional column stats ----------------
// 128x128 tile, 256 threads, 8x8 per thread

template<bool STATS, bool RESID>
__global__ __launch_bounds__(256, 2) void gemm_kernel(
    const float* __restrict__ A, const float* __restrict__ W,
    const float* __restrict__ bias, const float* __restrict__ R,
    float* __restrict__ C, int M,
    float* __restrict__ colsum, float* __restrict__ colsumsq)
{
  __shared__ float As[BK][LDSP];
  __shared__ float Bs[BK][LDSP];
  __shared__ float s_sum[BN];
  __shared__ float s_sq[BN];
  const int tid = threadIdx.x;
  const int tm8 = (tid >> 4) << 3;
  const int tn8 = (tid & 15) << 3;
  const int row0 = blockIdx.y * BM;
  const int col0 = blockIdx.x * BN;

  if (STATS){
    if (tid < BN){ s_sum[tid] = 0.f; s_sq[tid] = 0.f; }
  }

  const int lm = tid >> 1;        // 0..127 : A row within tile
  const int lk = (tid & 1) << 3;  // 0 or 8 : A k offset
  const int br = tid >> 4;        // 0..15  : B k row
  const int bc = (tid & 15) << 3; // B col offset

  float acc[8][8];
  #pragma unroll
  for (int i = 0; i < 8; ++i)
    #pragma unroll
    for (int j = 0; j < 8; ++j) acc[i][j] = 0.f;

  for (int kt = 0; kt < D; kt += BK){
    float4 a0 = make_float4(0.f,0.f,0.f,0.f), a1 = make_float4(0.f,0.f,0.f,0.f);
    int arow = row0 + lm;
    if (arow < M){
      const float* ap = A + (size_t)arow * D + kt + lk;
      a0 = *reinterpret_cast<const float4*>(ap);
      a1 = *reinterpret_cast<const float4*>(ap + 4);
    }
    As[lk+0][lm] = a0.x; As[lk+1][lm] = a0.y; As[lk+2][lm] = a0.z; As[lk+3][lm] = a0.w;
    As[lk+4][lm] = a1.x; As[lk+5][lm] = a1.y; As[lk+6][lm] = a1.z; As[lk+7][lm] = a1.w;
    const float* wp = W + (size_t)(kt + br) * D + col0 + bc;
    *reinterpret_cast<float4*>(&Bs[br][bc])     = *reinterpret_cast<const float4*>(wp);
    *reinterpret_cast<float4*>(&Bs[br][bc + 4]) = *reinterpret_cast<const float4*>(wp + 4);
    __syncthreads();
    #pragma unroll
    for (int kk = 0; kk < BK; ++kk){
      float a[8], b[8];
      *reinterpret_cast<float4*>(&a[0]) = *reinterpret_cast<const float4*>(&As[kk][tm8]);
      *reinterpret_cast<float4*>(&a[4]) = *reinterpret_cast<const float4*>(&As[kk][tm8 + 4]);
      *reinterpret_cast<float4*>(&b[0]) = *reinterpret_cast<const float4*>(&Bs[kk][tn8]);
      *reinterpret_cast<float4*>(&b[4]) = *reinterpret_cast<const float4*>(&Bs[kk][tn8 + 4]);
      #pragma unroll
      for (int i = 0; i < 8; ++i)
        #pragma unroll
        for (int j = 0; j < 8; ++j)
          acc[i][j] = fmaf(a[i], b[j], acc[i][j]);
    }
    __syncthreads();
  }

  float bv[8];
  *reinterpret_cast<float4*>(&bv[0]) = *reinterpret_cast<const float4*>(&bias[col0 + tn8]);
  *reinterpret_cast<float4*>(&bv[4]) = *reinterpret_cast<const float4*>(&bias[col0 + tn8 + 4]);

  float cs[8], cq[8];
  #pragma unroll
  for (int j = 0; j < 8; ++j){ cs[j] = 0.f; cq[j] = 0.f; }

  #pragma unroll
  for (int i = 0; i < 8; ++i){
    int row = row0 + tm8 + i;
    if (row < M){
      float v[8];
      #pragma unroll
      for (int j = 0; j < 8; ++j) v[j] = fmaxf(acc[i][j] + bv[j], 0.f);
      if (RESID){
        const float* rp = R + (size_t)row * D + col0 + tn8;
        float rv[8];
        *reinterpret_cast<float4*>(&rv[0]) = *reinterpret_cast<const float4*>(rp);
        *reinterpret_cast<float4*>(&rv[4]) = *reinterpret_cast<const float4*>(rp + 4);
        #pragma unroll
        for (int j = 0; j < 8; ++j) v[j] += rv[j];
      }
      if (STATS){
        #pragma unroll
        for (int j = 0; j < 8; ++j){ cs[j] += v[j]; cq[j] = fmaf(v[j], v[j], cq[j]); }
      }
      float* cp = C + (size_t)row * D + col0 + tn8;
      *reinterpret_cast<float4*>(cp)     = *reinterpret_cast<const float4*>(&v[0]);
      *reinterpret_cast<float4*>(cp + 4) = *reinterpret_cast<const float4*>(&v[4]);
    }
  }
  if (STATS){
    __syncthreads();
    #pragma unroll
    for (int j = 0; j < 8; ++j){
      atomicAdd(&s_sum[tn8 + j], cs[j]);
      atomicAdd(&s_sq[tn8 + j], cq[j]);
    }
    __syncthreads();
    if (tid < BN){
      atomicAdd(&colsum[col0 + tid], s_sum[tid]);
      atomicAdd(&colsumsq[col0 + tid], s_sq[tid]);
    }
  }
}

// ---------------- BN fold: W2' = scale_k * W2[k,:], b2' = b2 + sum_k shift_k W2[k,:] ----------------

__global__ void fold1_kernel(const float* __restrict__ colsum, const float* __restrict__ colsumsq,
                             const float* __restrict__ g, const float* __restrict__ bt,
                             float* __restrict__ scaleArr, float* __restrict__ shiftArr, int M){
  int k = threadIdx.x;
  float mu = colsum[k] / (float)M;
  float var = colsumsq[k] / (float)M - mu * mu;
  var = fmaxf(var, 0.f);
  float sc = g[k] * rsqrtf(var + 1e-5f);
  scaleArr[k] = sc;
  shiftArr[k] = bt[k] - mu * sc;
}

__global__ void fold2_kernel(const float* __restrict__ W2, const float* __restrict__ scaleArr,
                             float* __restrict__ W2p){
  int k = blockIdx.x, j = threadIdx.x;
  W2p[k * D + j] = scaleArr[k] * W2[k * D + j];
}

__global__ void fold3_kernel(const float* __restrict__ W2, const float* __restrict__ shiftArr,
                             const float* __restrict__ b2, float* __restrict__ b2p){
  int j = threadIdx.x;
  float acc = b2[j];
  for (int k = 0; k < D; ++k) acc = fmaf(shiftArr[k], W2[k * D + j], acc);
  b2p[j] = acc;
}

// ---------------- fc2: out[n] = dot(Y[n,:], w) + b ----------------

__global__ void fc2_kernel(const float4* __restrict__ Y, const float* __restrict__ w,
                           const float* __restrict__ b, float* __restrict__ out, int M){
  int gid = blockIdx.x * blockDim.x + threadIdx.x;
  int node = gid >> 6;
  int lane = gid & 63;
  if (node >= M) return;
  float4 y = Y[(size_t)node * 64 + lane];
  float4 wv = *reinterpret_cast<const float4*>(&w[lane << 2]);
  float s = y.x*wv.x + y.y*wv.y + y.z*wv.z + y.w*wv.w;
  #pragma unroll
  for (int off = 32; off > 0; off >>= 1) s += __shfl_down(s, off);
  if (lane == 0) out[node] = s + b[0];
}

// ---------------- host ----------------

extern "C" void kernel_launch(void* const* d_in, const int* in_sizes, int n_in,
                              void* d_out, int out_size, void* d_ws, size_t ws_size,
                              hipStream_t stream)
{
  const float* x_in = (const float*)d_in[0];
  const int*   ei   = (const int*)d_in[1];
  const float* W1s  = (const float*)d_in[2];
  const float* b1s  = (const float*)d_in[3];
  const float* gam  = (const float*)d_in[4];
  const float* bet  = (const float*)d_in[5];
  const float* W2s  = (const float*)d_in[6];
  const float* b2s  = (const float*)d_in[7];
  const float* fc1w = (const float*)d_in[8];
  const float* fc1b = (const float*)d_in[9];
  const float* fc2w = (const float*)d_in[10];
  const float* fc2b = (const float*)d_in[11];
  float* out = (float*)d_out;

  const int M = in_sizes[0] / D;
  const int E = in_sizes[1] / 2;
  const int L = in_sizes[2] / (D * D);

  char* ws = (char*)d_ws;
  size_t off = 0;
  auto alloc = [&](size_t bytes) -> void* {
    void* p = ws + off;
    off += (bytes + 255) & ~(size_t)255;
    return p;
  };
  float* bufA = (float*)alloc((size_t)M * D * 4);
  float* bufB = (float*)alloc((size_t)M * D * 4);
  float* bufS = (float*)alloc((size_t)M * D * 4);
  float* bufH = (float*)alloc((size_t)M * D * 4);
  int* rowptr = (int*)alloc((size_t)(M + 1) * 4);
  int* cnt    = (int*)alloc((size_t)M * 4);
  int* col    = (int*)alloc((size_t)E * 4);
  float* scaleArr = (float*)alloc(D * 4);
  float* shiftArr = (float*)alloc(D * 4);
  float* W2p  = (float*)alloc((size_t)D * D * 4);
  float* b2p  = (float*)alloc(D * 4);
  float* colsum = (float*)alloc(2 * D * 4);
  float* colsumsq = colsum + D;

  const int* srcArr = ei;
  const int* dstArr = ei + E;

  // CSR build (once per call; reused across layers)
  hipMemsetAsync(cnt, 0, (size_t)M * 4, stream);
  hist_kernel<<<(E + 255) / 256, 256, 0, stream>>>(dstArr, cnt, E);
  scan_kernel<<<1, 1024, 0, stream>>>(cnt, rowptr, M);
  copy_kernel<<<(M + 255) / 256, 256, 0, stream>>>(rowptr, cnt, M); // cnt -> cursor
  scatter_kernel<<<(E + 255) / 256, 256, 0, stream>>>(srcArr, dstArr, cnt, col, E);

  dim3 ggrid(D / BN, (M + BM - 1) / BM);
  const int aggGrid = (M * 64 + 255) / 256;

  for (int l = 0; l < L; ++l){
    const float* aggIn;
    float* outP;
    const float* resP;
    if ((l & 1) == 0){ // even layer: first of a residual block
      aggIn = (l == 0) ? x_in : bufA;
      outP = bufB;
      resP = nullptr;
    } else {           // odd layer: second of block, add residual
      aggIn = bufB;
      outP = bufA;
      resP = (l == 1) ? x_in : bufA;
    }
    agg_kernel<<<aggGrid, 256, 0, stream>>>((const float4*)aggIn, rowptr, col, (float4*)bufS, M);
    hipMemsetAsync(colsum, 0, 2 * D * 4, stream);
    gemm_kernel<true,false><<<ggrid, 256, 0, stream>>>(bufS, W1s + (size_t)l*D*D, b1s + (size_t)l*D,
                                                       nullptr, bufH, M, colsum, colsumsq);
    fold1_kernel<<<1, D, 0, stream>>>(colsum, colsumsq, gam + (size_t)l*D, bet + (size_t)l*D,
                                      scaleArr, shiftArr, M);
    fold2_kernel<<<D, D, 0, stream>>>(W2s + (size_t)l*D*D, scaleArr, W2p);
    fold3_kernel<<<1, D, 0, stream>>>(W2s + (size_t)l*D*D, shiftArr, b2s + (size_t)l*D, b2p);
    if (resP)
      gemm_kernel<false,true><<<ggrid, 256, 0, stream>>>(bufH, W2p, b2p, resP, outP, M, nullptr, nullptr);
    else
      gemm_kernel<false,false><<<ggrid, 256, 0, stream>>>(bufH, W2p, b2p, nullptr, outP, M, nullptr, nullptr);
  }

  // y = x + relu(x @ fc1 + b)
  gemm_kernel<false,true><<<ggrid, 256, 0, stream>>>(bufA, fc1w, fc1b, bufA, bufB, M, nullptr, nullptr);
  // out = y @ fc2 + b
  fc2_kernel<<<(M * 64 + 255) / 256, 256, 0, stream>>>((const float4*)bufB, fc2w, fc2b, out, M);
}